// Round 1
// baseline (1172.305 us; speedup 1.0000x reference)
//
#include <hip/hip_runtime.h>
#include <hip/hip_bf16.h>
#include <cstdint>
#include <cstddef>

typedef __bf16 bf16_t;
typedef bf16_t bf16x8 __attribute__((ext_vector_type(8)));
typedef bf16_t bf16x4 __attribute__((ext_vector_type(4)));
typedef float f32x4 __attribute__((ext_vector_type(4)));

#define NEG_BIG (-1e30f)

// ---------------- fp32 -> bf16 convert with K padding ----------------
__global__ __launch_bounds__(256) void convert_pad(const float* __restrict__ src,
                                                   bf16_t* __restrict__ dst,
                                                   int incols, int outcols) {
    const int row = blockIdx.x;
    const float* s = src + (size_t)row * incols;
    bf16_t* d = dst + (size_t)row * outcols;
    const int n4 = outcols >> 2;
    for (int c = threadIdx.x; c < n4; c += blockDim.x) {
        const int col = c << 2;
        float4 v;
        if (col < incols) v = *(const float4*)(s + col);   // incols % 4 == 0
        else              v = make_float4(0.f, 0.f, 0.f, 0.f);
        bf16x4 o;
        o[0] = (bf16_t)v.x; o[1] = (bf16_t)v.y; o[2] = (bf16_t)v.z; o[3] = (bf16_t)v.w;
        *(bf16x4*)(d + col) = o;
    }
}

// ---------------- bf16 GEMM: Z = A[M,K] @ W[N,K]^T + bias, Z bf16 ----------------
#define BM 128
#define BN 128
#define BK 32

__global__ __launch_bounds__(256) void gemm_bt(const bf16_t* __restrict__ A,
                                               const bf16_t* __restrict__ W,
                                               const float* __restrict__ bias,
                                               bf16_t* __restrict__ Z,
                                               int K, int N) {
    __shared__ __align__(16) bf16_t As[BM * BK];
    __shared__ __align__(16) bf16_t Bs[BN * BK];
    const int tid  = threadIdx.x;
    const int wid  = tid >> 6;
    const int lane = tid & 63;
    const int n0 = blockIdx.x * BN;
    const int m0 = blockIdx.y * BM;

    const int wm = (wid >> 1) * 64;   // wave row offset within tile
    const int wn = (wid & 1) * 64;    // wave col offset within tile

    f32x4 acc[4][4] = {};

    // staging: 8 instrs per tile; instr idx = wid*2+t covers rows [idx*16, idx*16+16)
    const int srow0 = wid * 32 + (lane >> 2);     // t=0 row; t=1 adds 16
    const int scol  = (lane & 3) * 8;             // element offset (8 bf16 = 16B)

    const bf16_t* Aptr0 = A + (size_t)(m0 + srow0) * K + scol;
    const bf16_t* Aptr1 = A + (size_t)(m0 + srow0 + 16) * K + scol;
    const bf16_t* Wptr0 = W + (size_t)(n0 + srow0) * K + scol;
    const bf16_t* Wptr1 = W + (size_t)(n0 + srow0 + 16) * K + scol;

    bf16_t* AsB0 = As + (wid * 2 + 0) * 512;   // wave-uniform LDS bases
    bf16_t* AsB1 = As + (wid * 2 + 1) * 512;
    bf16_t* BsB0 = Bs + (wid * 2 + 0) * 512;
    bf16_t* BsB1 = Bs + (wid * 2 + 1) * 512;

    for (int k0 = 0; k0 < K; k0 += BK) {
        __syncthreads();
        __builtin_amdgcn_global_load_lds((const __attribute__((address_space(1))) void*)(Aptr0 + k0),
                                         (__attribute__((address_space(3))) void*)AsB0, 16, 0, 0);
        __builtin_amdgcn_global_load_lds((const __attribute__((address_space(1))) void*)(Aptr1 + k0),
                                         (__attribute__((address_space(3))) void*)AsB1, 16, 0, 0);
        __builtin_amdgcn_global_load_lds((const __attribute__((address_space(1))) void*)(Wptr0 + k0),
                                         (__attribute__((address_space(3))) void*)BsB0, 16, 0, 0);
        __builtin_amdgcn_global_load_lds((const __attribute__((address_space(1))) void*)(Wptr1 + k0),
                                         (__attribute__((address_space(3))) void*)BsB1, 16, 0, 0);
        __syncthreads();

        const int arow = wm + (lane & 15);
        const int brow = wn + (lane & 15);
        const int koff = (lane >> 4) * 8;
        bf16x8 af[4], bfr[4];
        #pragma unroll
        for (int i = 0; i < 4; ++i)
            af[i] = *(const bf16x8*)(As + (arow + i * 16) * BK + koff);
        #pragma unroll
        for (int j = 0; j < 4; ++j)
            bfr[j] = *(const bf16x8*)(Bs + (brow + j * 16) * BK + koff);
        #pragma unroll
        for (int i = 0; i < 4; ++i)
            #pragma unroll
            for (int j = 0; j < 4; ++j)
                acc[i][j] = __builtin_amdgcn_mfma_f32_16x16x32_bf16(af[i], bfr[j], acc[i][j], 0, 0, 0);
    }

    // epilogue: C/D layout col=lane&15, row=(lane>>4)*4+r
    const int cq = lane >> 4;
    const int cl = lane & 15;
    #pragma unroll
    for (int j = 0; j < 4; ++j) {
        const int col = n0 + wn + j * 16 + cl;
        const float bj = bias[col];
        #pragma unroll
        for (int i = 0; i < 4; ++i) {
            const int row = m0 + wm + i * 16 + cq * 4;
            #pragma unroll
            for (int r = 0; r < 4; ++r)
                Z[(size_t)(row + r) * N + col] = (bf16_t)(acc[i][j][r] + bj);
        }
    }
}

// ---------------- mixed activation + dropout-mask + mask passthrough ----------------
// one block per row (H=1024, 256 threads x 4 cols)
__global__ __launch_bounds__(256) void act_kernel(const bf16_t* __restrict__ Z,
                                                  const float* __restrict__ mask,
                                                  const int* __restrict__ tids,
                                                  bf16_t* __restrict__ H,
                                                  float* __restrict__ mask_out) {
    const int row  = blockIdx.x;
    const int t    = threadIdx.x;
    const int wid  = t >> 6;
    const int lane = t & 63;
    __shared__ float r3[4], r4[4];
    __shared__ float bc[4];   // mx3, mx4, s3, s4

    const size_t base = (size_t)row * 1024 + t * 4;
    bf16x4 z4 = *(const bf16x4*)(Z + base);
    float z[4];
    #pragma unroll
    for (int j = 0; j < 4; ++j) z[j] = (float)z4[j];
    const int4 ty4 = *(const int4*)(tids + t * 4);
    const int ty[4] = {ty4.x, ty4.y, ty4.z, ty4.w};
    const float4 m4 = *(const float4*)(mask + base);
    const float mk[4] = {m4.x, m4.y, m4.z, m4.w};

    // pass 1: max over tid==3 (of z) and tid==4 (of -z)
    float mx3 = NEG_BIG, mx4 = NEG_BIG;
    #pragma unroll
    for (int j = 0; j < 4; ++j) {
        if (ty[j] == 3) mx3 = fmaxf(mx3, z[j]);
        if (ty[j] == 4) mx4 = fmaxf(mx4, -z[j]);
    }
    #pragma unroll
    for (int off = 32; off > 0; off >>= 1) {
        mx3 = fmaxf(mx3, __shfl_down(mx3, off));
        mx4 = fmaxf(mx4, __shfl_down(mx4, off));
    }
    if (lane == 0) { r3[wid] = mx3; r4[wid] = mx4; }
    __syncthreads();
    if (t == 0) {
        bc[0] = fmaxf(fmaxf(r3[0], r3[1]), fmaxf(r3[2], r3[3]));
        bc[1] = fmaxf(fmaxf(r4[0], r4[1]), fmaxf(r4[2], r4[3]));
    }
    __syncthreads();
    mx3 = bc[0]; mx4 = bc[1];

    // pass 2: sum of exp
    float s3 = 0.f, s4 = 0.f;
    #pragma unroll
    for (int j = 0; j < 4; ++j) {
        if (ty[j] == 3) s3 += __expf(z[j] - mx3);
        if (ty[j] == 4) s4 += __expf(-z[j] - mx4);
    }
    #pragma unroll
    for (int off = 32; off > 0; off >>= 1) {
        s3 += __shfl_down(s3, off);
        s4 += __shfl_down(s4, off);
    }
    if (lane == 0) { r3[wid] = s3; r4[wid] = s4; }
    __syncthreads();
    if (t == 0) {
        bc[2] = r3[0] + r3[1] + r3[2] + r3[3];
        bc[3] = r4[0] + r4[1] + r4[2] + r4[3];
    }
    __syncthreads();
    const float inv3 = 1.f / bc[2];   // inf if no tid==3 col: never used then
    const float inv4 = 1.f / bc[3];

    bf16x4 h4;
    #pragma unroll
    for (int j = 0; j < 4; ++j) {
        const float zz = z[j];
        const int tt = ty[j];
        float a;
        if (tt == 0)      a = fmaxf(zz, 0.f);
        else if (tt == 1) { const float e = __expf(-2.f * fabsf(zz));
                            const float th = (1.f - e) / (1.f + e);
                            a = (zz >= 0.f) ? th : -th; }
        else if (tt == 2) a = 1.f / (1.f + __expf(-zz));
        else if (tt == 3) a = __expf(zz - mx3) * inv3;
        else if (tt == 4) a = __expf(-zz - mx4) * inv4;
        else if (tt == 5) a = 0.5f * zz * (1.f + erff(zz * 0.70710678118654752f));
        else              a = (zz >= 0.f) ? zz : 0.01f * zz;
        h4[j] = (bf16_t)(a * mk[j] * 2.0f);   // KEEP_SCALE = 2
    }
    *(bf16x4*)(H + base) = h4;
    *(float4*)(mask_out + base) = m4;   // mask passthrough output
}

// ---------------- final layer: logits = H @ W3^T + b3, then log_softmax ----------------
__global__ __launch_bounds__(256) void final_layer(const bf16_t* __restrict__ H,
                                                   const float* __restrict__ W3,
                                                   const float* __restrict__ b3,
                                                   float* __restrict__ out) {
    __shared__ __align__(16) bf16_t Ws[10 * 1024];
    for (int i = threadIdx.x; i < 10240; i += 256) Ws[i] = (bf16_t)W3[i];
    __syncthreads();
    const int wid  = threadIdx.x >> 6;
    const int lane = threadIdx.x & 63;
    #pragma unroll 1
    for (int rr = 0; rr < 4; ++rr) {
        const int row = blockIdx.x * 16 + wid * 4 + rr;
        const bf16_t* hrow = H + (size_t)row * 1024;
        float acc[10];
        #pragma unroll
        for (int n = 0; n < 10; ++n) acc[n] = 0.f;
        #pragma unroll
        for (int c = 0; c < 2; ++c) {
            const int k = c * 512 + lane * 8;
            const bf16x8 hv = *(const bf16x8*)(hrow + k);
            float hf[8];
            #pragma unroll
            for (int j = 0; j < 8; ++j) hf[j] = (float)hv[j];
            #pragma unroll
            for (int n = 0; n < 10; ++n) {
                const bf16x8 wv = *(const bf16x8*)(Ws + n * 1024 + k);
                #pragma unroll
                for (int j = 0; j < 8; ++j) acc[n] += hf[j] * (float)wv[j];
            }
        }
        #pragma unroll
        for (int n = 0; n < 10; ++n)
            #pragma unroll
            for (int off = 32; off > 0; off >>= 1)
                acc[n] += __shfl_down(acc[n], off);
        if (lane == 0) {
            float lg[10]; float mx = -1e30f;
            #pragma unroll
            for (int n = 0; n < 10; ++n) { lg[n] = acc[n] + b3[n]; mx = fmaxf(mx, lg[n]); }
            float se = 0.f;
            #pragma unroll
            for (int n = 0; n < 10; ++n) se += __expf(lg[n] - mx);
            const float lse = logf(se) + mx;
            #pragma unroll
            for (int n = 0; n < 10; ++n) out[(size_t)row * 10 + n] = lg[n] - lse;
        }
    }
}

extern "C" void kernel_launch(void* const* d_in, const int* in_sizes, int n_in,
                              void* d_out, int out_size, void* d_ws, size_t ws_size,
                              hipStream_t stream) {
    (void)in_sizes; (void)n_in; (void)out_size; (void)ws_size;
    const float* x     = (const float*)d_in[0];
    const float* W0    = (const float*)d_in[1];
    const float* b0    = (const float*)d_in[2];
    const float* W1    = (const float*)d_in[3];
    const float* b1    = (const float*)d_in[4];
    const float* W2    = (const float*)d_in[5];
    const float* b2    = (const float*)d_in[6];
    const float* W3    = (const float*)d_in[7];
    const float* b3    = (const float*)d_in[8];
    const float* mask1 = (const float*)d_in[9];
    const float* mask2 = (const float*)d_in[10];
    const float* mask3 = (const float*)d_in[11];
    const int*   tids  = (const int*)d_in[12];

    float* out = (float*)d_out;
    float* mo1 = out + 327680;               // 32768*10
    float* mo2 = mo1 + 33554432;             // 32768*1024
    float* mo3 = mo2 + 33554432;

    char* ws = (char*)d_ws;
    bf16_t* xb  = (bf16_t*)ws;  ws += (size_t)32768 * 800 * 2;
    bf16_t* W0b = (bf16_t*)ws;  ws += (size_t)1024 * 800 * 2;
    bf16_t* W1b = (bf16_t*)ws;  ws += (size_t)1024 * 1024 * 2;
    bf16_t* W2b = (bf16_t*)ws;  ws += (size_t)1024 * 1024 * 2;
    bf16_t* Zb  = (bf16_t*)ws;  ws += (size_t)32768 * 1024 * 2;
    bf16_t* hb  = (bf16_t*)ws;  ws += (size_t)32768 * 1024 * 2;
    // total workspace: ~184 MiB

    convert_pad<<<32768, 256, 0, stream>>>(x,  xb,  784, 800);
    convert_pad<<<1024,  256, 0, stream>>>(W0, W0b, 784, 800);
    convert_pad<<<1024,  256, 0, stream>>>(W1, W1b, 1024, 1024);
    convert_pad<<<1024,  256, 0, stream>>>(W2, W2b, 1024, 1024);

    dim3 g(1024 / BN, 32768 / BM);   // (8, 256)
    gemm_bt<<<g, 256, 0, stream>>>(xb, W0b, b0, Zb, 800, 1024);
    act_kernel<<<32768, 256, 0, stream>>>(Zb, mask1, tids, hb, mo1);
    gemm_bt<<<g, 256, 0, stream>>>(hb, W1b, b1, Zb, 1024, 1024);
    act_kernel<<<32768, 256, 0, stream>>>(Zb, mask2, tids + 1024, hb, mo2);
    gemm_bt<<<g, 256, 0, stream>>>(hb, W2b, b2, Zb, 1024, 1024);
    act_kernel<<<32768, 256, 0, stream>>>(Zb, mask3, tids + 2048, hb, mo3);
    final_layer<<<2048, 256, 0, stream>>>(hb, W3, b3, out);
}